// Round 1
// baseline (15374.905 us; speedup 1.0000x reference)
//
#include <hip/hip_runtime.h>
#include <hip/hip_bf16.h>
#include <stdint.h>

#define T_SEQ 128
#define NBATCH 32
#define EMBED 512
#define HID 1024
#define NVOCAB 32000

typedef float f32x4 __attribute__((ext_vector_type(4)));
typedef short s16x8 __attribute__((ext_vector_type(8)));

__device__ __forceinline__ unsigned short f2bf(float f) {
  unsigned int u = __float_as_uint(f);
  u += 0x7FFFu + ((u >> 16) & 1u);   // round-to-nearest-even
  return (unsigned short)(u >> 16);
}

// ---------------- f32 -> bf16 convert (vectorized, grid-stride) ----------------
__global__ void k_f32_to_bf16(const float4* __restrict__ in,
                              ushort4* __restrict__ out, int n4) {
  int i = blockIdx.x * blockDim.x + threadIdx.x;
  int stride = gridDim.x * blockDim.x;
  for (; i < n4; i += stride) {
    float4 v = in[i];
    ushort4 o;
    o.x = f2bf(v.x); o.y = f2bf(v.y); o.z = f2bf(v.z); o.w = f2bf(v.w);
    out[i] = o;
  }
}

// ------------- embedding gather -> A0 bf16 [4096][512], row m = t*32+b -------------
__global__ void k_embed(const int* __restrict__ tok, const float* __restrict__ table,
                        ushort4* __restrict__ A0) {
  int tid = blockIdx.x * 256 + threadIdx.x;   // 4096*128 threads total
  int m = tid >> 7, kq = tid & 127;
  int b = m & 31, t = m >> 5;
  int tk = tok[b * T_SEQ + t];
  float4 v = *(const float4*)(table + (size_t)tk * EMBED + kq * 4);
  ushort4 o;
  o.x = f2bf(v.x); o.y = f2bf(v.y); o.z = f2bf(v.z); o.w = f2bf(v.w);
  A0[tid] = o;
}

// ---------------- bf16 MFMA GEMM: C[M,N] = A[M,K] * B[N,K]^T (+bias) ----------------
// 128x128 tile, BK=64, 4 waves, each wave 64x64 via 4x4 of 16x16x32 fragments.
// permute=1: output row m=(t*32+b) is written to row (b*128+t)  [for logits layout]
#define BM 128
#define BN 128
#define BKK 64

__global__ __launch_bounds__(256) void k_gemm_bt(
    const short* __restrict__ A,   // [M,K] bf16 bits
    const short* __restrict__ B,   // [N,K] bf16 bits
    float* __restrict__ C,
    const float* __restrict__ bias, // [N]
    int M, int N, int K, int permute)
{
  __shared__ short As[BM * BKK];
  __shared__ short Bs[BN * BKK];
  const int tid = threadIdx.x;
  const int w = tid >> 6, l = tid & 63;
  const int wr = w >> 1, wc = w & 1;
  const int bm = blockIdx.x * BM, bn = blockIdx.y * BN;
  const int l15 = l & 15, lkg = l >> 4;

  f32x4 acc[4][4] = {};

  for (int kt = 0; kt < K; kt += BKK) {
    // ---- stage A,B tiles (reg-staged, coalesced 16B per lane) ----
#pragma unroll
    for (int p = 0; p < 4; ++p) {
      int idx = p * 2048 + tid * 8;          // element index in [128*64)
      int r = idx >> 6, c = idx & 63;
      *(s16x8*)&As[idx] = *(const s16x8*)&A[(size_t)(bm + r) * K + kt + c];
      *(s16x8*)&Bs[idx] = *(const s16x8*)&B[(size_t)(bn + r) * K + kt + c];
    }
    __syncthreads();

#pragma unroll
    for (int ks = 0; ks < 2; ++ks) {
      s16x8 af[4], bfr[4];
#pragma unroll
      for (int mi = 0; mi < 4; ++mi)
        af[mi] = *(const s16x8*)&As[(wr * 64 + mi * 16 + l15) * BKK + ks * 32 + lkg * 8];
#pragma unroll
      for (int ni = 0; ni < 4; ++ni)
        bfr[ni] = *(const s16x8*)&Bs[(wc * 64 + ni * 16 + l15) * BKK + ks * 32 + lkg * 8];
#pragma unroll
      for (int mi = 0; mi < 4; ++mi)
#pragma unroll
        for (int ni = 0; ni < 4; ++ni)
          acc[mi][ni] = __builtin_amdgcn_mfma_f32_16x16x32_bf16(
              af[mi], bfr[ni], acc[mi][ni], 0, 0, 0);
    }
    __syncthreads();
  }

  // ---- epilogue: C/D layout col=lane&15, row=(lane>>4)*4+reg ----
  const int lr = lkg * 4;
#pragma unroll
  for (int mi = 0; mi < 4; ++mi) {
#pragma unroll
    for (int ni = 0; ni < 4; ++ni) {
      int col = bn + wc * 64 + ni * 16 + l15;
      float bv = bias ? bias[col] : 0.0f;
#pragma unroll
      for (int j = 0; j < 4; ++j) {
        int row = bm + wr * 64 + mi * 16 + lr + j;
        int orow = permute ? ((row & 31) * T_SEQ + (row >> 5)) : row;
        C[(size_t)orow * N + col] = acc[mi][ni][j] + bv;
      }
    }
  }
}

// ---------------- one GRU timestep (fp32), gates fused ----------------
// Thread (b, j, ks): partial dots of r,z,n rows over K-slice of 256; shfl-reduce
// across the 4 adjacent ks lanes; ks==0 lane applies gates and writes h_new.
// grid = 256 blocks (4 j per block), block = 512 threads.
__global__ __launch_bounds__(512) void k_gru_step(
    const float* __restrict__ gi_t,   // [32,3072]  (includes b_ih)
    const float* __restrict__ h_in,   // [32,1024]
    const float* __restrict__ W_hh,   // [3072,1024]
    const float* __restrict__ b_hh,   // [3072]
    float* __restrict__ h_out)        // [32,1024]
{
  const int tid = threadIdx.x;
  const int ks = tid & 3;
  const int b = (tid >> 2) & 31;
  const int jl = tid >> 7;
  const int j = blockIdx.x * 4 + jl;

  const float* __restrict__ hp = h_in + b * HID + ks * 256;
  const float* __restrict__ wr = W_hh + (size_t)j * HID + ks * 256;
  const float* __restrict__ wz = wr + (size_t)HID * HID;
  const float* __restrict__ wn = wz + (size_t)HID * HID;

  float ar = 0.f, az = 0.f, an = 0.f;
#pragma unroll 8
  for (int i = 0; i < 256; i += 4) {
    float4 h4 = *(const float4*)(hp + i);
    float4 r4 = *(const float4*)(wr + i);
    float4 z4 = *(const float4*)(wz + i);
    float4 n4 = *(const float4*)(wn + i);
    ar += h4.x * r4.x + h4.y * r4.y + h4.z * r4.z + h4.w * r4.w;
    az += h4.x * z4.x + h4.y * z4.y + h4.z * z4.z + h4.w * z4.w;
    an += h4.x * n4.x + h4.y * n4.y + h4.z * n4.z + h4.w * n4.w;
  }
  // reduce across k-slices (lanes differing in bits 0..1)
  ar += __shfl_xor(ar, 1); ar += __shfl_xor(ar, 2);
  az += __shfl_xor(az, 1); az += __shfl_xor(az, 2);
  an += __shfl_xor(an, 1); an += __shfl_xor(an, 2);

  if (ks == 0) {
    float ir  = gi_t[b * 3072 + j];
    float iz  = gi_t[b * 3072 + HID + j];
    float inn = gi_t[b * 3072 + 2 * HID + j];
    float hr = ar + b_hh[j];
    float hz = az + b_hh[HID + j];
    float hn = an + b_hh[2 * HID + j];
    float r = 1.0f / (1.0f + expf(-(ir + hr)));
    float z = 1.0f / (1.0f + expf(-(iz + hz)));
    float n = tanhf(inn + r * hn);
    float hprev = h_in[b * HID + j];
    h_out[b * HID + j] = (1.0f - z) * n + z * hprev;
  }
}

// ---------------- host ----------------
extern "C" void kernel_launch(void* const* d_in, const int* in_sizes, int n_in,
                              void* d_out, int out_size, void* d_ws, size_t ws_size,
                              hipStream_t stream)
{
  const int*   inputs = (const int*)d_in[0];
  // d_in[1] = lengths (unused by reference)
  const float* hidden = (const float*)d_in[2];
  const float* table  = (const float*)d_in[3];
  const float* Wih0   = (const float*)d_in[4];
  const float* Whh0   = (const float*)d_in[5];
  const float* bih0   = (const float*)d_in[6];
  const float* bhh0   = (const float*)d_in[7];
  const float* Wih1   = (const float*)d_in[8];
  const float* Whh1   = (const float*)d_in[9];
  const float* bih1   = (const float*)d_in[10];
  const float* bhh1   = (const float*)d_in[11];
  const float* Wout   = (const float*)d_in[12];
  const float* bout   = (const float*)d_in[13];
  float* out = (float*)d_out;

  char* ws = (char*)d_ws;
  size_t off = 0;
  auto alloc = [&](size_t bytes) {
    void* p = ws + off;
    off += (bytes + 255) & ~(size_t)255;
    return p;
  };
  float* gi0 = (float*)alloc((size_t)4096 * 3072 * 4);
  float* gi1 = (float*)alloc((size_t)4096 * 3072 * 4);
  float* ys0 = (float*)alloc((size_t)4096 * 1024 * 4);
  float* ys1 = (float*)alloc((size_t)4096 * 1024 * 4);
  short* A0  = (short*)alloc((size_t)4096 * 512 * 2);
  short* A1  = (short*)alloc((size_t)4096 * 1024 * 2);
  short* A2  = (short*)alloc((size_t)4096 * 1024 * 2);
  short* B0  = (short*)alloc((size_t)3072 * 512 * 2);
  short* B1  = (short*)alloc((size_t)3072 * 1024 * 2);
  short* B2  = (short*)alloc((size_t)32000 * 1024 * 2);

  // weight + input conversions (recomputed every call; deterministic)
  k_f32_to_bf16<<<1024, 256, 0, stream>>>((const float4*)Wih0, (ushort4*)B0, 3072 * 512 / 4);
  k_f32_to_bf16<<<1024, 256, 0, stream>>>((const float4*)Wih1, (ushort4*)B1, 3072 * 1024 / 4);
  k_f32_to_bf16<<<2048, 256, 0, stream>>>((const float4*)Wout, (ushort4*)B2, 32000 * 1024 / 4);
  k_embed<<<2048, 256, 0, stream>>>(inputs, table, (ushort4*)A0);

  // layer 0: input-side gates, then recurrence
  dim3 g0(32, 24);
  k_gemm_bt<<<g0, 256, 0, stream>>>(A0, B0, gi0, bih0, 4096, 3072, 512, 0);
  for (int t = 0; t < T_SEQ; ++t) {
    const float* hin = (t == 0) ? hidden : ys0 + (size_t)(t - 1) * NBATCH * HID;
    k_gru_step<<<256, 512, 0, stream>>>(gi0 + (size_t)t * NBATCH * 3 * HID, hin,
                                        Whh0, bhh0, ys0 + (size_t)t * NBATCH * HID);
  }

  // layer 1
  k_f32_to_bf16<<<1024, 256, 0, stream>>>((const float4*)ys0, (ushort4*)A1, 4096 * 1024 / 4);
  k_gemm_bt<<<g0, 256, 0, stream>>>(A1, B1, gi1, bih1, 4096, 3072, 1024, 0);
  for (int t = 0; t < T_SEQ; ++t) {
    const float* hin = (t == 0) ? hidden + NBATCH * HID : ys1 + (size_t)(t - 1) * NBATCH * HID;
    k_gru_step<<<256, 512, 0, stream>>>(gi1 + (size_t)t * NBATCH * 3 * HID, hin,
                                        Whh1, bhh1, ys1 + (size_t)t * NBATCH * HID);
  }

  // output projection: logits[b,s,v]  (row permutation folded into epilogue)
  k_f32_to_bf16<<<1024, 256, 0, stream>>>((const float4*)ys1, (ushort4*)A2, 4096 * 1024 / 4);
  dim3 g2(32, 250);
  k_gemm_bt<<<g2, 256, 0, stream>>>(A2, B2, out, bout, 4096, 32000, 1024, 1);
}

// Round 2
// 5201.574 us; speedup vs baseline: 2.9558x; 2.9558x over previous
//
#include <hip/hip_runtime.h>
#include <hip/hip_bf16.h>
#include <hip/hip_cooperative_groups.h>
#include <stdint.h>

namespace cg = cooperative_groups;

#define T_SEQ 128
#define NBATCH 32
#define EMBED 512
#define HID 1024
#define NVOCAB 32000

typedef float f32x4 __attribute__((ext_vector_type(4)));
typedef _Float16 f16x8 __attribute__((ext_vector_type(8)));

__device__ __forceinline__ unsigned short f2h(float f) {
  _Float16 h = (_Float16)f;
  return __builtin_bit_cast(unsigned short, h);
}
__device__ __forceinline__ float sigm(float x) {
  return 1.0f / (1.0f + __expf(-x));
}
__device__ __forceinline__ float tanh_fast(float x) {
  return 2.0f / (1.0f + __expf(-2.0f * x)) - 1.0f;
}

// ---------------- f32 -> f16 convert (vectorized, grid-stride) ----------------
__global__ void k_f32_to_f16(const float4* __restrict__ in,
                             ushort4* __restrict__ out, int n4) {
  int i = blockIdx.x * blockDim.x + threadIdx.x;
  int stride = gridDim.x * blockDim.x;
  for (; i < n4; i += stride) {
    float4 v = in[i];
    ushort4 o;
    o.x = f2h(v.x); o.y = f2h(v.y); o.z = f2h(v.z); o.w = f2h(v.w);
    out[i] = o;
  }
}

// ------------- embedding gather -> A0 f16 [4096][512], row m = t*32+b -------------
__global__ void k_embed(const int* __restrict__ tok, const float* __restrict__ table,
                        ushort4* __restrict__ A0) {
  int tid = blockIdx.x * 256 + threadIdx.x;   // 4096*128 threads total
  int m = tid >> 7, kq = tid & 127;
  int b = m & 31, t = m >> 5;
  int tk = tok[b * T_SEQ + t];
  float4 v = *(const float4*)(table + (size_t)tk * EMBED + kq * 4);
  ushort4 o;
  o.x = f2h(v.x); o.y = f2h(v.y); o.z = f2h(v.z); o.w = f2h(v.w);
  A0[tid] = o;
}

// ---------------- f16 MFMA GEMM: C[M,N] = A[M,K] * B[N,K]^T (+bias) ----------------
// 128x128 tile, BK=64, 4 waves, each wave 64x64 via 4x4 of 16x16x32 fragments.
// permute=1: output row m=(t*32+b) is written to row (b*128+t)  [for logits layout]
#define BM 128
#define BN 128
#define BKK 64

__global__ __launch_bounds__(256) void k_gemm_bt(
    const short* __restrict__ A,   // [M,K] f16 bits
    const short* __restrict__ B,   // [N,K] f16 bits
    float* __restrict__ C,
    const float* __restrict__ bias, // [N]
    int M, int N, int K, int permute)
{
  __shared__ __align__(16) short As[BM * BKK];
  __shared__ __align__(16) short Bs[BN * BKK];
  const int tid = threadIdx.x;
  const int w = tid >> 6, l = tid & 63;
  const int wr = w >> 1, wc = w & 1;
  const int bm = blockIdx.x * BM, bn = blockIdx.y * BN;
  const int l15 = l & 15, lkg = l >> 4;

  f32x4 acc[4][4] = {};

  for (int kt = 0; kt < K; kt += BKK) {
#pragma unroll
    for (int p = 0; p < 4; ++p) {
      int idx = p * 2048 + tid * 8;          // element index in [128*64)
      int r = idx >> 6, c = idx & 63;
      *(f16x8*)&As[idx] = *(const f16x8*)&A[(size_t)(bm + r) * K + kt + c];
      *(f16x8*)&Bs[idx] = *(const f16x8*)&B[(size_t)(bn + r) * K + kt + c];
    }
    __syncthreads();

#pragma unroll
    for (int ks = 0; ks < 2; ++ks) {
      f16x8 af[4], bfr[4];
#pragma unroll
      for (int mi = 0; mi < 4; ++mi)
        af[mi] = *(const f16x8*)&As[(wr * 64 + mi * 16 + l15) * BKK + ks * 32 + lkg * 8];
#pragma unroll
      for (int ni = 0; ni < 4; ++ni)
        bfr[ni] = *(const f16x8*)&Bs[(wc * 64 + ni * 16 + l15) * BKK + ks * 32 + lkg * 8];
#pragma unroll
      for (int mi = 0; mi < 4; ++mi)
#pragma unroll
        for (int ni = 0; ni < 4; ++ni)
          acc[mi][ni] = __builtin_amdgcn_mfma_f32_16x16x32_f16(
              af[mi], bfr[ni], acc[mi][ni], 0, 0, 0);
    }
    __syncthreads();
  }

  const int lr = lkg * 4;
#pragma unroll
  for (int mi = 0; mi < 4; ++mi) {
#pragma unroll
    for (int ni = 0; ni < 4; ++ni) {
      int col = bn + wc * 64 + ni * 16 + l15;
      float bv = bias ? bias[col] : 0.0f;
#pragma unroll
      for (int j = 0; j < 4; ++j) {
        int row = bm + wr * 64 + mi * 16 + lr + j;
        int orow = permute ? ((row & 31) * T_SEQ + (row >> 5)) : row;
        C[(size_t)orow * N + col] = acc[mi][ni][j] + bv;
      }
    }
  }
}

// ---------------- fused 2-layer GRU recurrence (persistent, cooperative) ----------------
// 256 blocks x 384 threads (6 waves). Block owns j in [4*bid, 4*bid+4).
// Wave w: role = w>>1 (0: W_hh0, 1: W_ih1, 2: W_hh1), nt = w&1 (b-half).
// Each wave keeps its 16x1024 f16 W-slice in registers as 32 MFMA A-fragments.
// Row order in the 16-tile: row = jj*4 + gate (gate: 0=r,1=z,2=n,3=pad) so the
// MFMA C/D layout (row=(l>>4)*4+reg, col=l&15) makes gate math lane-local.
// Pipeline: iter s: layer0 computes t=s; layer1 computes t=s-1. grid.sync per iter.
__global__ __launch_bounds__(384, 2) void k_gru_fused(
    const float* __restrict__ gi0,    // [128][32][3072] (includes b_ih0)
    const float* __restrict__ Whh0,   // [3072][1024]
    const float* __restrict__ bhh0,   // [3072]
    const float* __restrict__ Wih1,   // [3072][1024]
    const float* __restrict__ bih1,   // [3072]
    const float* __restrict__ Whh1,   // [3072][1024]
    const float* __restrict__ bhh1,   // [3072]
    const _Float16* __restrict__ h0i, // [32][1024]
    const _Float16* __restrict__ h1i, // [32][1024]
    _Float16* __restrict__ ys0f,      // [128][32][1024]
    _Float16* __restrict__ ys1f)      // [128][32][1024]
{
  __shared__ float bufIH[3][2][64];   // p1 -> p2 handoff of W_ih1 pre-activations

  const int tid = threadIdx.x;
  const int l = tid & 63;
  const int w = tid >> 6;
  const int role = w >> 1, nt = w & 1;
  const int j0 = blockIdx.x * 4;

  // A-fragment (operand) decode
  const int row16 = l & 15;
  const int jjr = row16 >> 2, gate = row16 & 3;
  const int koct = l >> 4;

  // output (C/D) decode
  const int b_out = nt * 16 + (l & 15);
  const int j_out = j0 + (l >> 4);

  // ---- load W slice into registers as f16 A-fragments ----
  const float* Wsrc = (role == 0) ? Whh0 : ((role == 1) ? Wih1 : Whh1);
  f16x8 af[32];
  if (gate < 3) {
    const float* wrow = Wsrc + (size_t)(gate * HID + j0 + jjr) * HID;
#pragma unroll
    for (int c = 0; c < 32; ++c) {
      float4 p0 = *(const float4*)(wrow + c * 32 + koct * 8);
      float4 p1 = *(const float4*)(wrow + c * 32 + koct * 8 + 4);
      f16x8 v = { (_Float16)p0.x, (_Float16)p0.y, (_Float16)p0.z, (_Float16)p0.w,
                  (_Float16)p1.x, (_Float16)p1.y, (_Float16)p1.z, (_Float16)p1.w };
      af[c] = v;
    }
  } else {
#pragma unroll
    for (int c = 0; c < 32; ++c) {
      f16x8 z = { (_Float16)0.f, (_Float16)0.f, (_Float16)0.f, (_Float16)0.f,
                  (_Float16)0.f, (_Float16)0.f, (_Float16)0.f, (_Float16)0.f };
      af[c] = z;
    }
  }

  // ---- per-lane bias preloads ----
  float bR = 0.f, bZ = 0.f, bN = 0.f, biR = 0.f, biZ = 0.f, biN = 0.f;
  if (role == 0) {
    bR = bhh0[j_out]; bZ = bhh0[HID + j_out]; bN = bhh0[2 * HID + j_out];
  } else if (role == 2) {
    bR = bhh1[j_out]; bZ = bhh1[HID + j_out]; bN = bhh1[2 * HID + j_out];
    biR = bih1[j_out]; biZ = bih1[HID + j_out]; biN = bih1[2 * HID + j_out];
  }

  // per-lane byte offset into a [32][1024] f16 slab for B-fragment loads
  const int bfragOff = (nt * 16 + (l & 15)) * 2048 + koct * 16;

  cg::grid_group grid = cg::this_grid();

  for (int s = 0; s <= T_SEQ; ++s) {
    // ---------- layer 0: t = s ----------
    if (role == 0 && s < T_SEQ) {
      const _Float16* hsrc = (s == 0) ? h0i : (ys0f + (size_t)(s - 1) * NBATCH * HID);
      const char* hb = (const char*)hsrc + bfragOff;
      f32x4 acc0 = {}, acc1 = {};
#pragma unroll
      for (int c = 0; c < 32; c += 2) {
        f16x8 bf0 = *(const f16x8*)(hb + c * 64);
        f16x8 bf1 = *(const f16x8*)(hb + c * 64 + 64);
        acc0 = __builtin_amdgcn_mfma_f32_16x16x32_f16(af[c], bf0, acc0, 0, 0, 0);
        acc1 = __builtin_amdgcn_mfma_f32_16x16x32_f16(af[c + 1], bf1, acc1, 0, 0, 0);
      }
      f32x4 acc = acc0 + acc1;

      const float* gib = gi0 + (size_t)(s * NBATCH + b_out) * 3072 + j_out;
      float ir = gib[0], iz = gib[HID], in_ = gib[2 * HID];
      float hp = (float)((s == 0) ? h0i[b_out * HID + j_out]
                                  : ys0f[(size_t)((s - 1) * NBATCH + b_out) * HID + j_out]);
      float r = sigm(ir + acc[0] + bR);
      float z = sigm(iz + acc[1] + bZ);
      float n = tanh_fast(in_ + r * (acc[2] + bN));
      float hnew = (1.0f - z) * n + z * hp;
      ys0f[(size_t)(s * NBATCH + b_out) * HID + j_out] = (_Float16)hnew;
    }

    // ---------- layer 1, input part: gi1 = W_ih1 * ys0[t1], t1 = s-1 ----------
    if (role == 1 && s >= 1) {
      const _Float16* hsrc = ys0f + (size_t)(s - 1) * NBATCH * HID;
      const char* hb = (const char*)hsrc + bfragOff;
      f32x4 acc0 = {}, acc1 = {};
#pragma unroll
      for (int c = 0; c < 32; c += 2) {
        f16x8 bf0 = *(const f16x8*)(hb + c * 64);
        f16x8 bf1 = *(const f16x8*)(hb + c * 64 + 64);
        acc0 = __builtin_amdgcn_mfma_f32_16x16x32_f16(af[c], bf0, acc0, 0, 0, 0);
        acc1 = __builtin_amdgcn_mfma_f32_16x16x32_f16(af[c + 1], bf1, acc1, 0, 0, 0);
      }
      f32x4 acc = acc0 + acc1;
      bufIH[0][nt][l] = acc[0];
      bufIH[1][nt][l] = acc[1];
      bufIH[2][nt][l] = acc[2];
    }

    __syncthreads();   // publish bufIH to role-2 waves

    // ---------- layer 1, hidden part + combine: t1 = s-1 ----------
    if (role == 2 && s >= 1) {
      const int t1 = s - 1;
      const _Float16* hsrc = (s == 1) ? h1i : (ys1f + (size_t)(s - 2) * NBATCH * HID);
      const char* hb = (const char*)hsrc + bfragOff;
      f32x4 acc0 = {}, acc1 = {};
#pragma unroll
      for (int c = 0; c < 32; c += 2) {
        f16x8 bf0 = *(const f16x8*)(hb + c * 64);
        f16x8 bf1 = *(const f16x8*)(hb + c * 64 + 64);
        acc0 = __builtin_amdgcn_mfma_f32_16x16x32_f16(af[c], bf0, acc0, 0, 0, 0);
        acc1 = __builtin_amdgcn_mfma_f32_16x16x32_f16(af[c + 1], bf1, acc1, 0, 0, 0);
      }
      f32x4 acc = acc0 + acc1;

      float ihR = bufIH[0][nt][l] + biR;
      float ihZ = bufIH[1][nt][l] + biZ;
      float ihN = bufIH[2][nt][l] + biN;
      float hp = (float)((s == 1) ? h1i[b_out * HID + j_out]
                                  : ys1f[(size_t)((s - 2) * NBATCH + b_out) * HID + j_out]);
      float r = sigm(ihR + acc[0] + bR);
      float z = sigm(ihZ + acc[1] + bZ);
      float n = tanh_fast(ihN + r * (acc[2] + bN));
      float hnew = (1.0f - z) * n + z * hp;
      ys1f[(size_t)(t1 * NBATCH + b_out) * HID + j_out] = (_Float16)hnew;
    }

    grid.sync();
  }
}

// ---------------- host ----------------
extern "C" void kernel_launch(void* const* d_in, const int* in_sizes, int n_in,
                              void* d_out, int out_size, void* d_ws, size_t ws_size,
                              hipStream_t stream)
{
  const int*   inputs = (const int*)d_in[0];
  const float* hidden = (const float*)d_in[2];
  const float* table  = (const float*)d_in[3];
  const float* Wih0   = (const float*)d_in[4];
  const float* Whh0   = (const float*)d_in[5];
  const float* bih0   = (const float*)d_in[6];
  const float* bhh0   = (const float*)d_in[7];
  const float* Wih1   = (const float*)d_in[8];
  const float* Whh1   = (const float*)d_in[9];
  const float* bih1   = (const float*)d_in[10];
  const float* bhh1   = (const float*)d_in[11];
  const float* Wout   = (const float*)d_in[12];
  const float* bout   = (const float*)d_in[13];
  float* out = (float*)d_out;

  char* ws = (char*)d_ws;
  size_t off = 0;
  auto alloc = [&](size_t bytes) {
    void* p = ws + off;
    off += (bytes + 255) & ~(size_t)255;
    return p;
  };
  float*     gi0  = (float*)alloc((size_t)4096 * 3072 * 4);       // 48 MB
  _Float16*  ys0f = (_Float16*)alloc((size_t)4096 * 1024 * 2);    // 8 MB
  _Float16*  ys1f = (_Float16*)alloc((size_t)4096 * 1024 * 2);    // 8 MB
  short*     A0   = (short*)alloc((size_t)4096 * 512 * 2);
  short*     B0   = (short*)alloc((size_t)3072 * 512 * 2);
  short*     B2   = (short*)alloc((size_t)32000 * 1024 * 2);      // 64 MB
  _Float16*  hcat = (_Float16*)alloc((size_t)2 * 32 * 1024 * 2);
  _Float16*  h0i  = hcat;
  _Float16*  h1i  = hcat + 32 * 1024;

  // conversions
  k_f32_to_f16<<<1024, 256, 0, stream>>>((const float4*)Wih0, (ushort4*)B0, 3072 * 512 / 4);
  k_f32_to_f16<<<2048, 256, 0, stream>>>((const float4*)Wout, (ushort4*)B2, 32000 * 1024 / 4);
  k_f32_to_f16<<<64, 256, 0, stream>>>((const float4*)hidden, (ushort4*)hcat, 2 * 32 * 1024 / 4);
  k_embed<<<2048, 256, 0, stream>>>(inputs, table, (ushort4*)A0);

  // layer-0 input-side gates: gi0 = A0 @ Wih0^T + bih0   [4096,3072]
  dim3 g0(32, 24);
  k_gemm_bt<<<g0, 256, 0, stream>>>(A0, B0, gi0, bih0, 4096, 3072, 512, 0);

  // fused 2-layer recurrence (cooperative)
  {
    void* kargs[] = {
      (void*)&gi0, (void*)&Whh0, (void*)&bhh0,
      (void*)&Wih1, (void*)&bih1, (void*)&Whh1, (void*)&bhh1,
      (void*)&h0i, (void*)&h1i, (void*)&ys0f, (void*)&ys1f
    };
    hipLaunchCooperativeKernel((const void*)k_gru_fused, dim3(256), dim3(384),
                               kargs, 0, stream);
  }

  // output projection: logits[b,s,v]  (row permutation folded into epilogue)
  dim3 g2(32, 250);
  k_gemm_bt<<<g2, 256, 0, stream>>>((const short*)ys1f, B2, out, bout, 4096, 32000, 1024, 1);
}

// Round 3
// 2609.380 us; speedup vs baseline: 5.8922x; 1.9934x over previous
//
#include <hip/hip_runtime.h>
#include <hip/hip_bf16.h>
#include <stdint.h>

#define T_SEQ 128
#define NBATCH 32
#define EMBED 512
#define HID 1024
#define NVOCAB 32000

typedef float f32x4 __attribute__((ext_vector_type(4)));
typedef _Float16 f16x8 __attribute__((ext_vector_type(8)));

__device__ __forceinline__ unsigned short f2h(float f) {
  _Float16 h = (_Float16)f;
  return __builtin_bit_cast(unsigned short, h);
}
__device__ __forceinline__ float sigm(float x) {
  return 1.0f / (1.0f + __expf(-x));
}
__device__ __forceinline__ float tanh_fast(float x) {
  return 2.0f / (1.0f + __expf(-2.0f * x)) - 1.0f;
}
__device__ __forceinline__ unsigned umin4(unsigned a, unsigned b, unsigned c, unsigned d) {
  unsigned x = a < b ? a : b;
  unsigned y = c < d ? c : d;
  return x < y ? x : y;
}

// ---------------- zero the sync flags (512 uints) ----------------
__global__ void k_zero(unsigned int* __restrict__ p, int n) {
  int i = blockIdx.x * blockDim.x + threadIdx.x;
  if (i < n) p[i] = 0;
}

// ---------------- f32 -> f16 convert (vectorized, grid-stride) ----------------
__global__ void k_f32_to_f16(const float4* __restrict__ in,
                             ushort4* __restrict__ out, int n4) {
  int i = blockIdx.x * blockDim.x + threadIdx.x;
  int stride = gridDim.x * blockDim.x;
  for (; i < n4; i += stride) {
    float4 v = in[i];
    ushort4 o;
    o.x = f2h(v.x); o.y = f2h(v.y); o.z = f2h(v.z); o.w = f2h(v.w);
    out[i] = o;
  }
}

// ------------- embedding gather -> A0 f16 [4096][512], row m = t*32+b -------------
__global__ void k_embed(const int* __restrict__ tok, const float* __restrict__ table,
                        ushort4* __restrict__ A0) {
  int tid = blockIdx.x * 256 + threadIdx.x;   // 4096*128 threads total
  int m = tid >> 7, kq = tid & 127;
  int b = m & 31, t = m >> 5;
  int tk = tok[b * T_SEQ + t];
  float4 v = *(const float4*)(table + (size_t)tk * EMBED + kq * 4);
  ushort4 o;
  o.x = f2h(v.x); o.y = f2h(v.y); o.z = f2h(v.z); o.w = f2h(v.w);
  A0[tid] = o;
}

// ---------------- f16 MFMA GEMM: C[M,N] = A[M,K] * B[N,K]^T (+bias) ----------------
// 128x128 tile, BK=64, 4 waves, each wave 64x64 via 4x4 of 16x16x32 fragments.
// permute=1: output row m=(t*32+b) is written to row (b*128+t)  [for logits layout]
#define BM 128
#define BN 128
#define BKK 64

__global__ __launch_bounds__(256) void k_gemm_bt(
    const short* __restrict__ A,   // [M,K] f16 bits
    const short* __restrict__ B,   // [N,K] f16 bits
    float* __restrict__ C,
    const float* __restrict__ bias, // [N]
    int M, int N, int K, int permute)
{
  __shared__ __align__(16) short As[BM * BKK];
  __shared__ __align__(16) short Bs[BN * BKK];
  const int tid = threadIdx.x;
  const int w = tid >> 6, l = tid & 63;
  const int wr = w >> 1, wc = w & 1;
  const int bm = blockIdx.x * BM, bn = blockIdx.y * BN;
  const int l15 = l & 15, lkg = l >> 4;

  f32x4 acc[4][4] = {};

  for (int kt = 0; kt < K; kt += BKK) {
#pragma unroll
    for (int p = 0; p < 4; ++p) {
      int idx = p * 2048 + tid * 8;          // element index in [128*64)
      int r = idx >> 6, c = idx & 63;
      *(f16x8*)&As[idx] = *(const f16x8*)&A[(size_t)(bm + r) * K + kt + c];
      *(f16x8*)&Bs[idx] = *(const f16x8*)&B[(size_t)(bn + r) * K + kt + c];
    }
    __syncthreads();

#pragma unroll
    for (int ks = 0; ks < 2; ++ks) {
      f16x8 af[4], bfr[4];
#pragma unroll
      for (int mi = 0; mi < 4; ++mi)
        af[mi] = *(const f16x8*)&As[(wr * 64 + mi * 16 + l15) * BKK + ks * 32 + lkg * 8];
#pragma unroll
      for (int ni = 0; ni < 4; ++ni)
        bfr[ni] = *(const f16x8*)&Bs[(wc * 64 + ni * 16 + l15) * BKK + ks * 32 + lkg * 8];
#pragma unroll
      for (int mi = 0; mi < 4; ++mi)
#pragma unroll
        for (int ni = 0; ni < 4; ++ni)
          acc[mi][ni] = __builtin_amdgcn_mfma_f32_16x16x32_f16(
              af[mi], bfr[ni], acc[mi][ni], 0, 0, 0);
    }
    __syncthreads();
  }

  const int lr = lkg * 4;
#pragma unroll
  for (int mi = 0; mi < 4; ++mi) {
#pragma unroll
    for (int ni = 0; ni < 4; ++ni) {
      int col = bn + wc * 64 + ni * 16 + l15;
      float bv = bias ? bias[col] : 0.0f;
#pragma unroll
      for (int j = 0; j < 4; ++j) {
        int row = bm + wr * 64 + mi * 16 + lr + j;
        int orow = permute ? ((row & 31) * T_SEQ + (row >> 5)) : row;
        C[(size_t)orow * N + col] = acc[mi][ni][j] + bv;
      }
    }
  }
}

// ---------------- fused 2-layer GRU recurrence (persistent, flag-synced) ----------------
// 256 blocks x 384 threads (6 waves). Block owns j in [4*bid, 4*bid+4).
// Wave w: role = w>>1 (0: W_hh0 @ step s, 1: W_ih1 @ step s-1, 2: W_hh1 @ step s-2),
// nt = w&1 (batch half). Weights live in registers as MFMA A-fragments.
// Sync: per-block monotonic counters flg0/flg1 (agent-scope atomics) replace
// grid.sync: producer publishes after release fence; wave 0 spin-polls all 256
// counters (4 per lane) and gates the block with __syncthreads.
// bufIH is double-buffered: role1@s writes parity s&1, role2@s reads parity (s-1)&1.
__global__ __launch_bounds__(384, 2) void k_gru_fused(
    const float* __restrict__ gi0,    // [128][32][3072] (includes b_ih0)
    const float* __restrict__ Whh0,   // [3072][1024]
    const float* __restrict__ bhh0,   // [3072]
    const float* __restrict__ Wih1,   // [3072][1024]
    const float* __restrict__ bih1,   // [3072]
    const float* __restrict__ Whh1,   // [3072][1024]
    const float* __restrict__ bhh1,   // [3072]
    const _Float16* __restrict__ h0i, // [32][1024]
    const _Float16* __restrict__ h1i, // [32][1024]
    _Float16* __restrict__ ys0f,      // [128][32][1024]
    _Float16* __restrict__ ys1f,      // [128][32][1024]
    unsigned int* flg0,               // [256]
    unsigned int* flg1)               // [256]
{
  __shared__ float bufIH[2][3][2][64];  // [parity][gate][nt][lane]

  const int tid = threadIdx.x;
  const int l = tid & 63;
  const int w = tid >> 6;
  const int role = w >> 1, nt = w & 1;
  const int bid = blockIdx.x;
  const int j0 = bid * 4;

  // A-fragment (operand) decode
  const int row16 = l & 15;
  const int jjr = row16 >> 2, gate = row16 & 3;
  const int koct = l >> 4;

  // output (C/D) decode
  const int b_out = nt * 16 + (l & 15);
  const int j_out = j0 + (l >> 4);

  // ---- load W slice into registers as f16 A-fragments ----
  const float* Wsrc = (role == 0) ? Whh0 : ((role == 1) ? Wih1 : Whh1);
  f16x8 af[32];
  if (gate < 3) {
    const float* wrow = Wsrc + (size_t)(gate * HID + j0 + jjr) * HID;
#pragma unroll
    for (int c = 0; c < 32; ++c) {
      float4 p0 = *(const float4*)(wrow + c * 32 + koct * 8);
      float4 p1 = *(const float4*)(wrow + c * 32 + koct * 8 + 4);
      f16x8 v = { (_Float16)p0.x, (_Float16)p0.y, (_Float16)p0.z, (_Float16)p0.w,
                  (_Float16)p1.x, (_Float16)p1.y, (_Float16)p1.z, (_Float16)p1.w };
      af[c] = v;
    }
  } else {
#pragma unroll
    for (int c = 0; c < 32; ++c) {
      f16x8 z = { (_Float16)0.f, (_Float16)0.f, (_Float16)0.f, (_Float16)0.f,
                  (_Float16)0.f, (_Float16)0.f, (_Float16)0.f, (_Float16)0.f };
      af[c] = z;
    }
  }

  // ---- per-lane bias preloads ----
  float bR = 0.f, bZ = 0.f, bN = 0.f, biR = 0.f, biZ = 0.f, biN = 0.f;
  if (role == 0) {
    bR = bhh0[j_out]; bZ = bhh0[HID + j_out]; bN = bhh0[2 * HID + j_out];
  } else if (role == 2) {
    bR = bhh1[j_out]; bZ = bhh1[HID + j_out]; bN = bhh1[2 * HID + j_out];
    biR = bih1[j_out]; biZ = bih1[HID + j_out]; biN = bih1[2 * HID + j_out];
  }

  // per-lane byte offset into a [32][1024] f16 slab for B-fragment loads
  const int bfragOff = b_out * 2048 + koct * 16;

  for (int s = 0; s <= T_SEQ + 1; ++s) {
    // ---- prefetch flag-independent gi0 values (role 0) ----
    float pre_ir = 0.f, pre_iz = 0.f, pre_in = 0.f;
    if (role == 0 && s < T_SEQ) {
      const float* gib = gi0 + (size_t)(s * NBATCH + b_out) * 3072 + j_out;
      pre_ir = gib[0]; pre_iz = gib[HID]; pre_in = gib[2 * HID];
    }

    // ---- wait for producers (wave 0 polls; block gated by barrier) ----
    if (w == 0) {
      unsigned need0 = (s >= 1 && s <= T_SEQ) ? (unsigned)s : 0u;       // ys0f[s-1]
      unsigned need1 = (s >= 3) ? (unsigned)(s - 2) : 0u;               // ys1f[s-3]
      if ((need0 | need1) != 0u) {
        const unsigned* f0 = flg0 + l * 4;
        const unsigned* f1 = flg1 + l * 4;
        for (;;) {
          unsigned m0 = 0xffffffffu, m1 = 0xffffffffu;
          if (need0) {
            unsigned a0 = __hip_atomic_load(f0 + 0, __ATOMIC_RELAXED, __HIP_MEMORY_SCOPE_AGENT);
            unsigned a1 = __hip_atomic_load(f0 + 1, __ATOMIC_RELAXED, __HIP_MEMORY_SCOPE_AGENT);
            unsigned a2 = __hip_atomic_load(f0 + 2, __ATOMIC_RELAXED, __HIP_MEMORY_SCOPE_AGENT);
            unsigned a3 = __hip_atomic_load(f0 + 3, __ATOMIC_RELAXED, __HIP_MEMORY_SCOPE_AGENT);
            m0 = umin4(a0, a1, a2, a3);
          }
          if (need1) {
            unsigned a0 = __hip_atomic_load(f1 + 0, __ATOMIC_RELAXED, __HIP_MEMORY_SCOPE_AGENT);
            unsigned a1 = __hip_atomic_load(f1 + 1, __ATOMIC_RELAXED, __HIP_MEMORY_SCOPE_AGENT);
            unsigned a2 = __hip_atomic_load(f1 + 2, __ATOMIC_RELAXED, __HIP_MEMORY_SCOPE_AGENT);
            unsigned a3 = __hip_atomic_load(f1 + 3, __ATOMIC_RELAXED, __HIP_MEMORY_SCOPE_AGENT);
            m1 = umin4(a0, a1, a2, a3);
          }
          if (__all(m0 >= need0 && m1 >= need1)) break;
          __builtin_amdgcn_s_sleep(1);
        }
        __builtin_amdgcn_fence(__ATOMIC_ACQUIRE, "agent");
      }
    }
    __syncthreads();

    // ---------- role 0: layer-0 step t = s ----------
    if (role == 0 && s < T_SEQ) {
      const _Float16* hsrc = (s == 0) ? h0i : (ys0f + (size_t)(s - 1) * NBATCH * HID);
      const char* hb = (const char*)hsrc + bfragOff;
      f32x4 acc0 = {}, acc1 = {};
#pragma unroll
      for (int c = 0; c < 32; c += 2) {
        f16x8 bf0 = *(const f16x8*)(hb + c * 64);
        f16x8 bf1 = *(const f16x8*)(hb + c * 64 + 64);
        acc0 = __builtin_amdgcn_mfma_f32_16x16x32_f16(af[c], bf0, acc0, 0, 0, 0);
        acc1 = __builtin_amdgcn_mfma_f32_16x16x32_f16(af[c + 1], bf1, acc1, 0, 0, 0);
      }
      f32x4 acc = acc0 + acc1;

      float hp = (float)((s == 0) ? h0i[b_out * HID + j_out]
                                  : ys0f[(size_t)((s - 1) * NBATCH + b_out) * HID + j_out]);
      float r = sigm(pre_ir + acc[0] + bR);
      float z = sigm(pre_iz + acc[1] + bZ);
      float n = tanh_fast(pre_in + r * (acc[2] + bN));
      float hnew = (1.0f - z) * n + z * hp;
      ys0f[(size_t)(s * NBATCH + b_out) * HID + j_out] = (_Float16)hnew;
    }

    // ---------- role 1: layer-1 input gates for t1 = s-1 -> bufIH[s&1] ----------
    if (role == 1 && s >= 1 && s <= T_SEQ) {
      const _Float16* hsrc = ys0f + (size_t)(s - 1) * NBATCH * HID;
      const char* hb = (const char*)hsrc + bfragOff;
      f32x4 acc0 = {}, acc1 = {};
#pragma unroll
      for (int c = 0; c < 32; c += 2) {
        f16x8 bf0 = *(const f16x8*)(hb + c * 64);
        f16x8 bf1 = *(const f16x8*)(hb + c * 64 + 64);
        acc0 = __builtin_amdgcn_mfma_f32_16x16x32_f16(af[c], bf0, acc0, 0, 0, 0);
        acc1 = __builtin_amdgcn_mfma_f32_16x16x32_f16(af[c + 1], bf1, acc1, 0, 0, 0);
      }
      f32x4 acc = acc0 + acc1;
      bufIH[s & 1][0][nt][l] = acc[0];
      bufIH[s & 1][1][nt][l] = acc[1];
      bufIH[s & 1][2][nt][l] = acc[2];
    }

    // ---------- role 2: layer-1 hidden + combine for t1 = s-2 ----------
    if (role == 2 && s >= 2) {
      const int t1 = s - 2;
      const _Float16* hsrc = (t1 == 0) ? h1i : (ys1f + (size_t)(t1 - 1) * NBATCH * HID);
      const char* hb = (const char*)hsrc + bfragOff;
      f32x4 acc0 = {}, acc1 = {};
#pragma unroll
      for (int c = 0; c < 32; c += 2) {
        f16x8 bf0 = *(const f16x8*)(hb + c * 64);
        f16x8 bf1 = *(const f16x8*)(hb + c * 64 + 64);
        acc0 = __builtin_amdgcn_mfma_f32_16x16x32_f16(af[c], bf0, acc0, 0, 0, 0);
        acc1 = __builtin_amdgcn_mfma_f32_16x16x32_f16(af[c + 1], bf1, acc1, 0, 0, 0);
      }
      f32x4 acc = acc0 + acc1;

      const int par = (s - 1) & 1;
      float ihR = bufIH[par][0][nt][l] + biR;
      float ihZ = bufIH[par][1][nt][l] + biZ;
      float ihN = bufIH[par][2][nt][l] + biN;
      float hp = (float)((t1 == 0) ? h1i[b_out * HID + j_out]
                                   : ys1f[(size_t)((t1 - 1) * NBATCH + b_out) * HID + j_out]);
      float r = sigm(ihR + acc[0] + bR);
      float z = sigm(ihZ + acc[1] + bZ);
      float n = tanh_fast(ihN + r * (acc[2] + bN));
      float hnew = (1.0f - z) * n + z * hp;
      ys1f[(size_t)(t1 * NBATCH + b_out) * HID + j_out] = (_Float16)hnew;
    }

    __syncthreads();   // drains each wave's stores (vmcnt 0) + publishes bufIH

    if (tid == 0) {
      __builtin_amdgcn_fence(__ATOMIC_RELEASE, "agent");
      if (s < T_SEQ)
        __hip_atomic_store(&flg0[bid], (unsigned)(s + 1), __ATOMIC_RELAXED, __HIP_MEMORY_SCOPE_AGENT);
      if (s >= 2)
        __hip_atomic_store(&flg1[bid], (unsigned)(s - 1), __ATOMIC_RELAXED, __HIP_MEMORY_SCOPE_AGENT);
    }
  }
}

// ---------------- host ----------------
extern "C" void kernel_launch(void* const* d_in, const int* in_sizes, int n_in,
                              void* d_out, int out_size, void* d_ws, size_t ws_size,
                              hipStream_t stream)
{
  const int*   inputs = (const int*)d_in[0];
  const float* hidden = (const float*)d_in[2];
  const float* table  = (const float*)d_in[3];
  const float* Wih0   = (const float*)d_in[4];
  const float* Whh0   = (const float*)d_in[5];
  const float* bih0   = (const float*)d_in[6];
  const float* bhh0   = (const float*)d_in[7];
  const float* Wih1   = (const float*)d_in[8];
  const float* Whh1   = (const float*)d_in[9];
  const float* bih1   = (const float*)d_in[10];
  const float* bhh1   = (const float*)d_in[11];
  const float* Wout   = (const float*)d_in[12];
  const float* bout   = (const float*)d_in[13];
  float* out = (float*)d_out;

  char* ws = (char*)d_ws;
  size_t off = 0;
  auto alloc = [&](size_t bytes) {
    void* p = ws + off;
    off += (bytes + 255) & ~(size_t)255;
    return p;
  };
  float*     gi0  = (float*)alloc((size_t)4096 * 3072 * 4);       // 48 MB
  _Float16*  ys0f = (_Float16*)alloc((size_t)4096 * 1024 * 2);    // 8 MB
  _Float16*  ys1f = (_Float16*)alloc((size_t)4096 * 1024 * 2);    // 8 MB
  short*     A0   = (short*)alloc((size_t)4096 * 512 * 2);
  short*     B0   = (short*)alloc((size_t)3072 * 512 * 2);
  short*     B2   = (short*)alloc((size_t)32000 * 1024 * 2);      // 64 MB
  _Float16*  hcat = (_Float16*)alloc((size_t)2 * 32 * 1024 * 2);
  _Float16*  h0i  = hcat;
  _Float16*  h1i  = hcat + 32 * 1024;
  unsigned int* flg0 = (unsigned int*)alloc(256 * 4);
  unsigned int* flg1 = (unsigned int*)alloc(256 * 4);

  // zero sync flags first (stream-ordered before the recurrence)
  k_zero<<<1, 512, 0, stream>>>(flg0, 512);

  // conversions
  k_f32_to_f16<<<1024, 256, 0, stream>>>((const float4*)Wih0, (ushort4*)B0, 3072 * 512 / 4);
  k_f32_to_f16<<<2048, 256, 0, stream>>>((const float4*)Wout, (ushort4*)B2, 32000 * 1024 / 4);
  k_f32_to_f16<<<64, 256, 0, stream>>>((const float4*)hidden, (ushort4*)hcat, 2 * 32 * 1024 / 4);
  k_embed<<<2048, 256, 0, stream>>>(inputs, table, (ushort4*)A0);

  // layer-0 input-side gates: gi0 = A0 @ Wih0^T + bih0   [4096,3072]
  dim3 g0(32, 24);
  k_gemm_bt<<<g0, 256, 0, stream>>>(A0, B0, gi0, bih0, 4096, 3072, 512, 0);

  // fused 2-layer recurrence (cooperative launch for co-residency; flag-based sync)
  {
    void* kargs[] = {
      (void*)&gi0, (void*)&Whh0, (void*)&bhh0,
      (void*)&Wih1, (void*)&bih1, (void*)&Whh1, (void*)&bhh1,
      (void*)&h0i, (void*)&h1i, (void*)&ys0f, (void*)&ys1f,
      (void*)&flg0, (void*)&flg1
    };
    hipLaunchCooperativeKernel((const void*)k_gru_fused, dim3(256), dim3(384),
                               kargs, 0, stream);
  }

  // output projection: logits[b,s,v]  (row permutation folded into epilogue)
  dim3 g2(32, 250);
  k_gemm_bt<<<g2, 256, 0, stream>>>((const short*)ys1f, B2, out, bout, 4096, 32000, 1024, 1);
}

// Round 4
// 1580.737 us; speedup vs baseline: 9.7264x; 1.6507x over previous
//
#include <hip/hip_runtime.h>
#include <hip/hip_bf16.h>
#include <stdint.h>

#define T_SEQ 128
#define NBATCH 32
#define EMBED 512
#define HID 1024
#define NVOCAB 32000

typedef float f32x4 __attribute__((ext_vector_type(4)));
typedef _Float16 f16x8 __attribute__((ext_vector_type(8)));

__device__ __forceinline__ unsigned short f2h(float f) {
  _Float16 h = (_Float16)f;
  return __builtin_bit_cast(unsigned short, h);
}
__device__ __forceinline__ float sigm(float x) {
  return 1.0f / (1.0f + __expf(-x));
}
__device__ __forceinline__ float tanh_fast(float x) {
  return 2.0f / (1.0f + __expf(-2.0f * x)) - 1.0f;
}
__device__ __forceinline__ unsigned umin4(unsigned a, unsigned b, unsigned c, unsigned d) {
  unsigned x = a < b ? a : b;
  unsigned y = c < d ? c : d;
  return x < y ? x : y;
}

// ---------------- zero the sync flags (512 uints) ----------------
__global__ void k_zero(unsigned int* __restrict__ p, int n) {
  int i = blockIdx.x * blockDim.x + threadIdx.x;
  if (i < n) p[i] = 0;
}

// ---------------- f32 -> f16 convert (vectorized, grid-stride) ----------------
__global__ void k_f32_to_f16(const float4* __restrict__ in,
                             ushort4* __restrict__ out, int n4) {
  int i = blockIdx.x * blockDim.x + threadIdx.x;
  int stride = gridDim.x * blockDim.x;
  for (; i < n4; i += stride) {
    float4 v = in[i];
    ushort4 o;
    o.x = f2h(v.x); o.y = f2h(v.y); o.z = f2h(v.z); o.w = f2h(v.w);
    out[i] = o;
  }
}

// ------------- embedding gather -> A0 f16 [4096][512], row m = t*32+b -------------
__global__ void k_embed(const int* __restrict__ tok, const float* __restrict__ table,
                        ushort4* __restrict__ A0) {
  int tid = blockIdx.x * 256 + threadIdx.x;   // 4096*128 threads total
  int m = tid >> 7, kq = tid & 127;
  int b = m & 31, t = m >> 5;
  int tk = tok[b * T_SEQ + t];
  float4 v = *(const float4*)(table + (size_t)tk * EMBED + kq * 4);
  ushort4 o;
  o.x = f2h(v.x); o.y = f2h(v.y); o.z = f2h(v.z); o.w = f2h(v.w);
  A0[tid] = o;
}

// ---------------- f16 MFMA GEMM: C[M,N] = A[M,K] * B[N,K]^T (+bias) ----------------
// 128x128 tile, BK=64, 4 waves, each wave 64x64 via 4x4 of 16x16x32 fragments.
// permute=1: output row m=(t*32+b) is written to row (b*128+t)  [for logits layout]
#define BM 128
#define BN 128
#define BKK 64

__global__ __launch_bounds__(256) void k_gemm_bt(
    const short* __restrict__ A,   // [M,K] f16 bits
    const short* __restrict__ B,   // [N,K] f16 bits
    float* __restrict__ C,
    const float* __restrict__ bias, // [N]
    int M, int N, int K, int permute)
{
  __shared__ __align__(16) short As[BM * BKK];
  __shared__ __align__(16) short Bs[BN * BKK];
  const int tid = threadIdx.x;
  const int w = tid >> 6, l = tid & 63;
  const int wr = w >> 1, wc = w & 1;
  const int bm = blockIdx.x * BM, bn = blockIdx.y * BN;
  const int l15 = l & 15, lkg = l >> 4;

  f32x4 acc[4][4] = {};

  for (int kt = 0; kt < K; kt += BKK) {
#pragma unroll
    for (int p = 0; p < 4; ++p) {
      int idx = p * 2048 + tid * 8;          // element index in [128*64)
      int r = idx >> 6, c = idx & 63;
      *(f16x8*)&As[idx] = *(const f16x8*)&A[(size_t)(bm + r) * K + kt + c];
      *(f16x8*)&Bs[idx] = *(const f16x8*)&B[(size_t)(bn + r) * K + kt + c];
    }
    __syncthreads();

#pragma unroll
    for (int ks = 0; ks < 2; ++ks) {
      f16x8 af[4], bfr[4];
#pragma unroll
      for (int mi = 0; mi < 4; ++mi)
        af[mi] = *(const f16x8*)&As[(wr * 64 + mi * 16 + l15) * BKK + ks * 32 + lkg * 8];
#pragma unroll
      for (int ni = 0; ni < 4; ++ni)
        bfr[ni] = *(const f16x8*)&Bs[(wc * 64 + ni * 16 + l15) * BKK + ks * 32 + lkg * 8];
#pragma unroll
      for (int mi = 0; mi < 4; ++mi)
#pragma unroll
        for (int ni = 0; ni < 4; ++ni)
          acc[mi][ni] = __builtin_amdgcn_mfma_f32_16x16x32_f16(
              af[mi], bfr[ni], acc[mi][ni], 0, 0, 0);
    }
    __syncthreads();
  }

  const int lr = lkg * 4;
#pragma unroll
  for (int mi = 0; mi < 4; ++mi) {
#pragma unroll
    for (int ni = 0; ni < 4; ++ni) {
      int col = bn + wc * 64 + ni * 16 + l15;
      float bv = bias ? bias[col] : 0.0f;
#pragma unroll
      for (int j = 0; j < 4; ++j) {
        int row = bm + wr * 64 + mi * 16 + lr + j;
        int orow = permute ? ((row & 31) * T_SEQ + (row >> 5)) : row;
        C[(size_t)orow * N + col] = acc[mi][ni][j] + bv;
      }
    }
  }
}

// ---------------- fused 2-layer GRU recurrence (persistent, flag-synced) ----------------
// 256 blocks x 384 threads (6 waves). Block owns j in [4*bid, 4*bid+4).
// Wave w: role = w>>1 (0: W_hh0 @ step s, 1: W_ih1 @ step s-1, 2: W_hh1 @ step s-2),
// nt = w&1 (batch half). Weights live in registers as MFMA A-fragments.
//
// Sync (fence-free): h values are PUBLISHED with agent-scope relaxed atomic
// stores (sc1 write-through -> L3 coherence point; two f16 packed per dword).
// __syncthreads drains each wave's vmcnt (stores at coherence point) before
// tid0 publishes the per-block flag (also sc1). Consumers poll flags with
// relaxed agent loads, then use PLAIN cached loads for h: every step reads a
// fresh address range, so no stale L1/L2 line can exist. No buffer_wbl2 /
// buffer_inv anywhere -> no per-iter L2 destruction.
__global__ __launch_bounds__(384, 2) void k_gru_fused(
    const float* __restrict__ gi0,    // [128][32][3072] (includes b_ih0)
    const float* __restrict__ Whh0,   // [3072][1024]
    const float* __restrict__ bhh0,   // [3072]
    const float* __restrict__ Wih1,   // [3072][1024]
    const float* __restrict__ bih1,   // [3072]
    const float* __restrict__ Whh1,   // [3072][1024]
    const float* __restrict__ bhh1,   // [3072]
    const _Float16* __restrict__ h0i, // [32][1024]
    const _Float16* __restrict__ h1i, // [32][1024]
    _Float16* __restrict__ ys0f,      // [128][32][1024]
    _Float16* __restrict__ ys1f,      // [128][32][1024]
    unsigned int* flg0,               // [256]
    unsigned int* flg1)               // [256]
{
  __shared__ float bufIH[2][3][2][64];  // [parity][gate][nt][lane]

  const int tid = threadIdx.x;
  const int l = tid & 63;
  const int w = tid >> 6;
  const int role = w >> 1, nt = w & 1;
  const int bid = blockIdx.x;
  const int j0 = bid * 4;

  // A-fragment (operand) decode
  const int row16 = l & 15;
  const int jjr = row16 >> 2, gate = row16 & 3;
  const int koct = l >> 4;

  // output (C/D) decode
  const int b_out = nt * 16 + (l & 15);
  const int j_out = j0 + (l >> 4);
  const int jj_even = (((l >> 4) & 1) == 0);

  // ---- load W slice into registers as f16 A-fragments ----
  const float* Wsrc = (role == 0) ? Whh0 : ((role == 1) ? Wih1 : Whh1);
  f16x8 af[32];
  if (gate < 3) {
    const float* wrow = Wsrc + (size_t)(gate * HID + j0 + jjr) * HID;
#pragma unroll
    for (int c = 0; c < 32; ++c) {
      float4 p0 = *(const float4*)(wrow + c * 32 + koct * 8);
      float4 p1 = *(const float4*)(wrow + c * 32 + koct * 8 + 4);
      f16x8 v = { (_Float16)p0.x, (_Float16)p0.y, (_Float16)p0.z, (_Float16)p0.w,
                  (_Float16)p1.x, (_Float16)p1.y, (_Float16)p1.z, (_Float16)p1.w };
      af[c] = v;
    }
  } else {
#pragma unroll
    for (int c = 0; c < 32; ++c) {
      f16x8 z = { (_Float16)0.f, (_Float16)0.f, (_Float16)0.f, (_Float16)0.f,
                  (_Float16)0.f, (_Float16)0.f, (_Float16)0.f, (_Float16)0.f };
      af[c] = z;
    }
  }

  // ---- per-lane bias preloads ----
  float bR = 0.f, bZ = 0.f, bN = 0.f, biR = 0.f, biZ = 0.f, biN = 0.f;
  if (role == 0) {
    bR = bhh0[j_out]; bZ = bhh0[HID + j_out]; bN = bhh0[2 * HID + j_out];
  } else if (role == 2) {
    bR = bhh1[j_out]; bZ = bhh1[HID + j_out]; bN = bhh1[2 * HID + j_out];
    biR = bih1[j_out]; biZ = bih1[HID + j_out]; biN = bih1[2 * HID + j_out];
  }

  // per-lane byte offset into a [32][1024] f16 slab for B-fragment loads
  const int bfragOff = b_out * 2048 + koct * 16;

  for (int s = 0; s <= T_SEQ + 1; ++s) {
    // ---- prefetch flag-independent gi0 values (role 0) ----
    float pre_ir = 0.f, pre_iz = 0.f, pre_in = 0.f;
    if (role == 0 && s < T_SEQ) {
      const float* gib = gi0 + (size_t)(s * NBATCH + b_out) * 3072 + j_out;
      pre_ir = gib[0]; pre_iz = gib[HID]; pre_in = gib[2 * HID];
    }

    // ---- wait for producers (wave 0 polls; block gated by barrier) ----
    if (w == 0) {
      unsigned need0 = (s >= 1 && s <= T_SEQ) ? (unsigned)s : 0u;       // ys0f[s-1]
      unsigned need1 = (s >= 3) ? (unsigned)(s - 2) : 0u;               // ys1f[s-3]
      if ((need0 | need1) != 0u) {
        const unsigned* f0 = flg0 + l * 4;
        const unsigned* f1 = flg1 + l * 4;
        for (;;) {
          unsigned m0 = 0xffffffffu, m1 = 0xffffffffu;
          if (need0) {
            unsigned a0 = __hip_atomic_load(f0 + 0, __ATOMIC_RELAXED, __HIP_MEMORY_SCOPE_AGENT);
            unsigned a1 = __hip_atomic_load(f0 + 1, __ATOMIC_RELAXED, __HIP_MEMORY_SCOPE_AGENT);
            unsigned a2 = __hip_atomic_load(f0 + 2, __ATOMIC_RELAXED, __HIP_MEMORY_SCOPE_AGENT);
            unsigned a3 = __hip_atomic_load(f0 + 3, __ATOMIC_RELAXED, __HIP_MEMORY_SCOPE_AGENT);
            m0 = umin4(a0, a1, a2, a3);
          }
          if (need1) {
            unsigned a0 = __hip_atomic_load(f1 + 0, __ATOMIC_RELAXED, __HIP_MEMORY_SCOPE_AGENT);
            unsigned a1 = __hip_atomic_load(f1 + 1, __ATOMIC_RELAXED, __HIP_MEMORY_SCOPE_AGENT);
            unsigned a2 = __hip_atomic_load(f1 + 2, __ATOMIC_RELAXED, __HIP_MEMORY_SCOPE_AGENT);
            unsigned a3 = __hip_atomic_load(f1 + 3, __ATOMIC_RELAXED, __HIP_MEMORY_SCOPE_AGENT);
            m1 = umin4(a0, a1, a2, a3);
          }
          if (__all(m0 >= need0 && m1 >= need1)) break;
          __builtin_amdgcn_s_sleep(1);
        }
        asm volatile("" ::: "memory");   // compiler barrier; HW issue order + fresh
                                         // addresses make an acquire fence unnecessary
      }
    }
    __syncthreads();

    // ---------- role 0: layer-0 step t = s ----------
    if (role == 0 && s < T_SEQ) {
      const _Float16* hsrc = (s == 0) ? h0i : (ys0f + (size_t)(s - 1) * NBATCH * HID);
      const char* hb = (const char*)hsrc + bfragOff;
      f32x4 acc0 = {}, acc1 = {};
#pragma unroll
      for (int c = 0; c < 32; c += 2) {
        f16x8 bf0 = *(const f16x8*)(hb + c * 64);
        f16x8 bf1 = *(const f16x8*)(hb + c * 64 + 64);
        acc0 = __builtin_amdgcn_mfma_f32_16x16x32_f16(af[c], bf0, acc0, 0, 0, 0);
        acc1 = __builtin_amdgcn_mfma_f32_16x16x32_f16(af[c + 1], bf1, acc1, 0, 0, 0);
      }
      f32x4 acc = acc0 + acc1;

      float hp = (float)((s == 0) ? h0i[b_out * HID + j_out]
                                  : ys0f[(size_t)((s - 1) * NBATCH + b_out) * HID + j_out]);
      float r = sigm(pre_ir + acc[0] + bR);
      float z = sigm(pre_iz + acc[1] + bZ);
      float n = tanh_fast(pre_in + r * (acc[2] + bN));
      float hnew = (1.0f - z) * n + z * hp;

      // publish h0[s]: pack two adjacent-j f16 into one dword, sc1 store
      unsigned bits = (unsigned)f2h(hnew);
      unsigned hi = __shfl_down(bits, 16);
      if (jj_even) {
        unsigned packed = (bits & 0xffffu) | (hi << 16);
        __hip_atomic_store((unsigned*)(ys0f + (size_t)(s * NBATCH + b_out) * HID + j_out),
                           packed, __ATOMIC_RELAXED, __HIP_MEMORY_SCOPE_AGENT);
      }
    }

    // ---------- role 1: layer-1 input gates for t1 = s-1 -> bufIH[s&1] ----------
    if (role == 1 && s >= 1 && s <= T_SEQ) {
      const _Float16* hsrc = ys0f + (size_t)(s - 1) * NBATCH * HID;
      const char* hb = (const char*)hsrc + bfragOff;
      f32x4 acc0 = {}, acc1 = {};
#pragma unroll
      for (int c = 0; c < 32; c += 2) {
        f16x8 bf0 = *(const f16x8*)(hb + c * 64);
        f16x8 bf1 = *(const f16x8*)(hb + c * 64 + 64);
        acc0 = __builtin_amdgcn_mfma_f32_16x16x32_f16(af[c], bf0, acc0, 0, 0, 0);
        acc1 = __builtin_amdgcn_mfma_f32_16x16x32_f16(af[c + 1], bf1, acc1, 0, 0, 0);
      }
      f32x4 acc = acc0 + acc1;
      bufIH[s & 1][0][nt][l] = acc[0];
      bufIH[s & 1][1][nt][l] = acc[1];
      bufIH[s & 1][2][nt][l] = acc[2];
    }

    // ---------- role 2: layer-1 hidden + combine for t1 = s-2 ----------
    if (role == 2 && s >= 2) {
      const int t1 = s - 2;
      const _Float16* hsrc = (t1 == 0) ? h1i : (ys1f + (size_t)(t1 - 1) * NBATCH * HID);
      const char* hb = (const char*)hsrc + bfragOff;
      f32x4 acc0 = {}, acc1 = {};
#pragma unroll
      for (int c = 0; c < 32; c += 2) {
        f16x8 bf0 = *(const f16x8*)(hb + c * 64);
        f16x8 bf1 = *(const f16x8*)(hb + c * 64 + 64);
        acc0 = __builtin_amdgcn_mfma_f32_16x16x32_f16(af[c], bf0, acc0, 0, 0, 0);
        acc1 = __builtin_amdgcn_mfma_f32_16x16x32_f16(af[c + 1], bf1, acc1, 0, 0, 0);
      }
      f32x4 acc = acc0 + acc1;

      const int par = (s - 1) & 1;
      float ihR = bufIH[par][0][nt][l] + biR;
      float ihZ = bufIH[par][1][nt][l] + biZ;
      float ihN = bufIH[par][2][nt][l] + biN;
      float hp = (float)((t1 == 0) ? h1i[b_out * HID + j_out]
                                   : ys1f[(size_t)((t1 - 1) * NBATCH + b_out) * HID + j_out]);
      float r = sigm(ihR + acc[0] + bR);
      float z = sigm(ihZ + acc[1] + bZ);
      float n = tanh_fast(ihN + r * (acc[2] + bN));
      float hnew = (1.0f - z) * n + z * hp;

      unsigned bits = (unsigned)f2h(hnew);
      unsigned hi = __shfl_down(bits, 16);
      if (jj_even) {
        unsigned packed = (bits & 0xffffu) | (hi << 16);
        __hip_atomic_store((unsigned*)(ys1f + (size_t)(t1 * NBATCH + b_out) * HID + j_out),
                           packed, __ATOMIC_RELAXED, __HIP_MEMORY_SCOPE_AGENT);
      }
    }

    // each wave drains its own vmcnt before s_barrier (compiler-inserted), so all
    // sc1 data stores are at the coherence point before tid0 publishes the flags
    __syncthreads();

    if (tid == 0) {
      if (s < T_SEQ)
        __hip_atomic_store(&flg0[bid], (unsigned)(s + 1), __ATOMIC_RELAXED, __HIP_MEMORY_SCOPE_AGENT);
      if (s >= 2)
        __hip_atomic_store(&flg1[bid], (unsigned)(s - 1), __ATOMIC_RELAXED, __HIP_MEMORY_SCOPE_AGENT);
    }
  }
}

// ---------------- host ----------------
extern "C" void kernel_launch(void* const* d_in, const int* in_sizes, int n_in,
                              void* d_out, int out_size, void* d_ws, size_t ws_size,
                              hipStream_t stream)
{
  const int*   inputs = (const int*)d_in[0];
  const float* hidden = (const float*)d_in[2];
  const float* table  = (const float*)d_in[3];
  const float* Wih0   = (const float*)d_in[4];
  const float* Whh0   = (const float*)d_in[5];
  const float* bih0   = (const float*)d_in[6];
  const float* bhh0   = (const float*)d_in[7];
  const float* Wih1   = (const float*)d_in[8];
  const float* Whh1   = (const float*)d_in[9];
  const float* bih1   = (const float*)d_in[10];
  const float* bhh1   = (const float*)d_in[11];
  const float* Wout   = (const float*)d_in[12];
  const float* bout   = (const float*)d_in[13];
  float* out = (float*)d_out;

  char* ws = (char*)d_ws;
  size_t off = 0;
  auto alloc = [&](size_t bytes) {
    void* p = ws + off;
    off += (bytes + 255) & ~(size_t)255;
    return p;
  };
  float*     gi0  = (float*)alloc((size_t)4096 * 3072 * 4);       // 48 MB
  _Float16*  ys0f = (_Float16*)alloc((size_t)4096 * 1024 * 2);    // 8 MB
  _Float16*  ys1f = (_Float16*)alloc((size_t)4096 * 1024 * 2);    // 8 MB
  short*     A0   = (short*)alloc((size_t)4096 * 512 * 2);
  short*     B0   = (short*)alloc((size_t)3072 * 512 * 2);
  short*     B2   = (short*)alloc((size_t)32000 * 1024 * 2);      // 64 MB
  _Float16*  hcat = (_Float16*)alloc((size_t)2 * 32 * 1024 * 2);
  _Float16*  h0i  = hcat;
  _Float16*  h1i  = hcat + 32 * 1024;
  unsigned int* flg0 = (unsigned int*)alloc(256 * 4);
  unsigned int* flg1 = (unsigned int*)alloc(256 * 4);

  // zero sync flags first (stream-ordered before the recurrence; covers flg0+flg1)
  k_zero<<<1, 512, 0, stream>>>(flg0, 512);

  // conversions
  k_f32_to_f16<<<1024, 256, 0, stream>>>((const float4*)Wih0, (ushort4*)B0, 3072 * 512 / 4);
  k_f32_to_f16<<<2048, 256, 0, stream>>>((const float4*)Wout, (ushort4*)B2, 32000 * 1024 / 4);
  k_f32_to_f16<<<64, 256, 0, stream>>>((const float4*)hidden, (ushort4*)hcat, 2 * 32 * 1024 / 4);
  k_embed<<<2048, 256, 0, stream>>>(inputs, table, (ushort4*)A0);

  // layer-0 input-side gates: gi0 = A0 @ Wih0^T + bih0   [4096,3072]
  dim3 g0(32, 24);
  k_gemm_bt<<<g0, 256, 0, stream>>>(A0, B0, gi0, bih0, 4096, 3072, 512, 0);

  // fused 2-layer recurrence (cooperative launch for co-residency; flag-based sync)
  {
    void* kargs[] = {
      (void*)&gi0, (void*)&Whh0, (void*)&bhh0,
      (void*)&Wih1, (void*)&bih1, (void*)&Whh1, (void*)&bhh1,
      (void*)&h0i, (void*)&h1i, (void*)&ys0f, (void*)&ys1f,
      (void*)&flg0, (void*)&flg1
    };
    hipLaunchCooperativeKernel((const void*)k_gru_fused, dim3(256), dim3(384),
                               kargs, 0, stream);
  }

  // output projection: logits[b,s,v]  (row permutation folded into epilogue)
  dim3 g2(32, 250);
  k_gemm_bt<<<g2, 256, 0, stream>>>((const short*)ys1f, B2, out, bout, 4096, 32000, 1024, 1);
}